// Round 7
// baseline (420.561 us; speedup 1.0000x reference)
//
#include <hip/hip_runtime.h>
#include <hip/hip_bf16.h>

#define HID 128
#define EXP 3
#define TOP 4
#define OUTC 64
#define POOL_CHUNK 128

typedef __bf16 bf16x8 __attribute__((ext_vector_type(8)));
typedef float f32x16 __attribute__((ext_vector_type(16)));
typedef _Float16 half4 __attribute__((ext_vector_type(4)));

#define GLDS_STRIDE 272              // 128 bf16 = 256B + 16B pad
#define GLDS_TILE (64 * GLDS_STRIDE) // 17408 B per tile (hi, lo)

// ---------------- CSR build ----------------

__global__ void count_kernel(const int* __restrict__ dst, int* __restrict__ cnt, int E) {
    int i = blockIdx.x * blockDim.x + threadIdx.x;
    if (i < E) atomicAdd(&cnt[dst[i]], 1);
}

__global__ void dinv_kernel(const int* __restrict__ cnt, float* __restrict__ dinv, int N) {
    int n = blockIdx.x * blockDim.x + threadIdx.x;
    if (n < N) dinv[n] = rsqrtf((float)cnt[n] + 1.0f);
}

// ---------------- hierarchical scan ----------------

__global__ __launch_bounds__(256) void scan_local_kernel(const int* __restrict__ cnt,
                                                         int* __restrict__ row_ptr,
                                                         int* __restrict__ bsum, int N) {
    __shared__ int sh[256];
    int b = blockIdx.x;
    int t = threadIdx.x;
    int base = b * 1024 + t * 4;
    int v[4] = {0, 0, 0, 0};
    if (base + 3 < N) {
        int4 c = *(const int4*)(cnt + base);
        v[0] = c.x; v[1] = c.y; v[2] = c.z; v[3] = c.w;
    } else {
#pragma unroll
        for (int k = 0; k < 4; ++k) if (base + k < N) v[k] = cnt[base + k];
    }
    int s = v[0] + v[1] + v[2] + v[3];
    sh[t] = s;
    __syncthreads();
    for (int off = 1; off < 256; off <<= 1) {
        int u = (t >= off) ? sh[t - off] : 0;
        __syncthreads();
        sh[t] += u;
        __syncthreads();
    }
    int run = sh[t] - s;
#pragma unroll
    for (int k = 0; k < 4; ++k) {
        if (base + k < N) row_ptr[base + k] = run;
        run += v[k];
    }
    if (t == 255) bsum[b] = sh[255];
}

__global__ __launch_bounds__(64) void scan_bsum_kernel(int* __restrict__ bsum, int nb,
                                                       int* __restrict__ total) {
    int t = threadIdx.x;
    int carry = 0;
    for (int base = 0; base < nb; base += 64) {
        int i = base + t;
        int v = (i < nb) ? bsum[i] : 0;
        int s = v;
#pragma unroll
        for (int off = 1; off < 64; off <<= 1) {
            int u = __shfl_up(s, off, 64);
            if (t >= off) s += u;
        }
        if (i < nb) bsum[i] = s - v + carry;
        carry += __shfl(s, 63, 64);
    }
    if (t == 0) *total = carry;
}

__global__ __launch_bounds__(256) void scan_fixup_kernel(const int* __restrict__ bsum,
                                                         const int* __restrict__ total,
                                                         int* __restrict__ row_ptr,
                                                         int* __restrict__ cursor, int N) {
    int b = blockIdx.x;
    int t = threadIdx.x;
    int off = bsum[b];
    int base = b * 1024 + t * 4;
#pragma unroll
    for (int k = 0; k < 4; ++k) {
        int i = base + k;
        if (i < N) {
            int r = row_ptr[i] + off;
            row_ptr[i] = r;
            cursor[i] = r;
        }
    }
    if (b == 0 && t == 0) row_ptr[N] = *total;
}

// XCD-sliced fill (keeps a node's CSR line owned by one slice of blocks)
__global__ void fill_kernel(const int* __restrict__ src, const int* __restrict__ dst,
                            int* __restrict__ cursor, const float* __restrict__ dinv,
                            int2* __restrict__ erec, int E) {
    int slice = blockIdx.x & 7;
    int i = (blockIdx.x >> 3) * blockDim.x + threadIdx.x;
    if (i >= E) return;
    int d = dst[i];
    if (((d >> 6) & 7) != slice) return;
    int s = src[i];
    int p = atomicAdd(&cursor[d], 1);
    erec[p] = make_int2(s, __float_as_int(dinv[s] * dinv[d]));
}

// ---------------- gates ----------------

__global__ void gates_kernel(const float* __restrict__ tf, const float* __restrict__ Wg0,
                             const float* __restrict__ Wg1, float* __restrict__ gates, int N) {
    int n = blockIdx.x * blockDim.x + threadIdx.x;
    if (n >= N) return;
    float4 t = *(const float4*)(tf + (size_t)n * TOP);
    const float* Wg[2] = {Wg0, Wg1};
#pragma unroll
    for (int l = 0; l < 2; ++l) {
        float lg[EXP];
#pragma unroll
        for (int e = 0; e < EXP; ++e) {
            const float* w = Wg[l] + e * TOP;
            lg[e] = (t.x * w[0] + t.y * w[1] + t.z * w[2] + t.w * w[3]) * (1.0f / 101.0f);
        }
        float m = fmaxf(lg[0], fmaxf(lg[1], lg[2]));
        float e0 = expf(lg[0] - m), e1 = expf(lg[1] - m), e2 = expf(lg[2] - m);
        float inv = 1.0f / (e0 + e1 + e2);
        gates[n * 6 + l * 3 + 0] = e0 * inv;
        gates[n * 6 + l * 3 + 1] = e1 * inv;
        gates[n * 6 + l * 3 + 2] = e2 * inv;
    }
}

// ---------------- fp32 -> fp16 shadow ----------------

__global__ void f32_to_f16_kernel(const float* __restrict__ x, _Float16* __restrict__ y,
                                  int total4) {
    int i = blockIdx.x * blockDim.x + threadIdx.x;
    if (i >= total4) return;
    float4 v = ((const float4*)x)[i];
    half4 h = {(_Float16)v.x, (_Float16)v.y, (_Float16)v.z, (_Float16)v.w};
    ((half4*)y)[i] = h;
}

// ---------------- W pack: B-fragment lane order, bf16 hi/lo ----------------

__global__ __launch_bounds__(64) void pack_w_kernel(const float* __restrict__ W0,
                                                    const float* __restrict__ W1,
                                                    __bf16* __restrict__ ph0, __bf16* __restrict__ pl0,
                                                    __bf16* __restrict__ ph1, __bf16* __restrict__ pl1) {
    int bid = blockIdx.x;           // 0..191
    int layer = bid / 96;
    int rem = bid % 96;
    int e = rem / 32;
    int s = (rem % 32) / 4;
    int c = rem % 4;
    const float* W = layer ? W1 : W0;
    __bf16* ph = layer ? ph1 : ph0;
    __bf16* pl = layer ? pl1 : pl0;
    int l = threadIdx.x;
    size_t dstbase = (size_t)((((e * 8 + s) * 4 + c) * 64 + l)) * 8;
    int kbase = s * 16 + (l >> 5) * 8;
    int n = c * 32 + (l & 31);
#pragma unroll
    for (int j = 0; j < 8; ++j) {
        float w = W[(size_t)e * (HID * HID) + (size_t)(kbase + j) * HID + n];
        __bf16 h = (__bf16)w;
        __bf16 lo = (__bf16)(w - (float)h);
        ph[dstbase + j] = h;
        pl[dstbase + j] = lo;
    }
}

// ---------------- aggregation: ag = A_hat @ h16, output bf16 hi/lo ----------------

__global__ __launch_bounds__(128) void aggregate_kernel(const _Float16* __restrict__ h16,
                                                        __bf16* __restrict__ aghi,
                                                        __bf16* __restrict__ aglo,
                                                        const int* __restrict__ row_ptr,
                                                        const int2* __restrict__ erec,
                                                        const float* __restrict__ dinv, int N) {
    __shared__ float red[2][HID];
    int n = blockIdx.x;
    int t = threadIdx.x;
    int c4 = t & 31;
    int es = t >> 5;
    int s = row_ptr[n], e = row_ptr[n + 1];

    float4 acc = make_float4(0.f, 0.f, 0.f, 0.f);
    int i = s + es;
    for (; i + 4 < e; i += 8) {
        int2 r0 = erec[i], r1 = erec[i + 4];
        float w0 = __int_as_float(r0.y), w1 = __int_as_float(r1.y);
        half4 v0 = *(const half4*)(h16 + (size_t)r0.x * HID + c4 * 4);
        half4 v1 = *(const half4*)(h16 + (size_t)r1.x * HID + c4 * 4);
        acc.x += (float)v0.x * w0 + (float)v1.x * w1;
        acc.y += (float)v0.y * w0 + (float)v1.y * w1;
        acc.z += (float)v0.z * w0 + (float)v1.z * w1;
        acc.w += (float)v0.w * w0 + (float)v1.w * w1;
    }
    if (i < e) {
        int2 r0 = erec[i];
        float w0 = __int_as_float(r0.y);
        half4 v0 = *(const half4*)(h16 + (size_t)r0.x * HID + c4 * 4);
        acc.x += (float)v0.x * w0; acc.y += (float)v0.y * w0;
        acc.z += (float)v0.z * w0; acc.w += (float)v0.w * w0;
    }

    acc.x += __shfl_xor(acc.x, 32, 64);
    acc.y += __shfl_xor(acc.y, 32, 64);
    acc.z += __shfl_xor(acc.z, 32, 64);
    acc.w += __shfl_xor(acc.w, 32, 64);
    int wv = t >> 6;
    int lane = t & 63;
    if (lane < 32) *(float4*)(&red[wv][lane * 4]) = acc;
    __syncthreads();

    float dn = dinv[n];
    float a = red[0][t] + red[1][t] + (float)h16[(size_t)n * HID + t] * dn * dn;
    size_t idx = (size_t)n * HID + t;
    __bf16 h = (__bf16)a;
    aghi[idx] = h;
    aglo[idx] = (__bf16)(a - (float)h);
}

// ---------------- MFMA fused 3-expert GEMM + relu + gate ----------------
// 64-row tile / block; 4 waves: wave w -> rows 32*(w&1), cols 64*(w>>1).
// 34 KB LDS, ~64 acc VGPRs -> 4 blocks/CU for latency hiding.

__global__ __launch_bounds__(256, 4) void expert_gemm_mfma_kernel(
        const __bf16* __restrict__ aghi, const __bf16* __restrict__ aglo,
        const __bf16* __restrict__ wpkh, const __bf16* __restrict__ wpkl,
        const float* __restrict__ bias, const float* __restrict__ gates, int gate_off,
        float* __restrict__ hout32, _Float16* __restrict__ hout16, int N) {
    __shared__ char lds[2 * GLDS_TILE];
    int tid = threadIdx.x;
    int row0 = blockIdx.x * 64;

    // stage 64 rows (hi, lo): 1024 16B-chunks each
#pragma unroll
    for (int it = 0; it < 4; ++it) {
        int id = tid + it * 256;
        int r = id >> 4;
        int c = id & 15;
        int gr = row0 + r;
        float4 vh = make_float4(0.f, 0.f, 0.f, 0.f);
        float4 vl = vh;
        if (gr < N) {
            vh = ((const float4*)aghi)[(size_t)gr * 16 + c];
            vl = ((const float4*)aglo)[(size_t)gr * 16 + c];
        }
        *(float4*)(lds + r * GLDS_STRIDE + c * 16) = vh;
        *(float4*)(lds + GLDS_TILE + r * GLDS_STRIDE + c * 16) = vl;
    }
    __syncthreads();

    int lane = tid & 63;
    int wave = tid >> 6;
    int m = lane & 31;
    int g = lane >> 5;
    int rhalf = wave & 1;
    int chalf = wave >> 1;
    const char* arow = lds + (rhalf * 32 + m) * GLDS_STRIDE + g * 16;
    int rowbase = row0 + rhalf * 32 + 4 * g;

    float F[2][16];
#pragma unroll
    for (int c = 0; c < 2; ++c)
#pragma unroll
        for (int r = 0; r < 16; ++r) F[c][r] = 0.f;

    for (int e = 0; e < EXP; ++e) {
        f32x16 acc[2];
#pragma unroll
        for (int c = 0; c < 2; ++c)
#pragma unroll
            for (int r = 0; r < 16; ++r) acc[c][r] = 0.f;

#pragma unroll
        for (int s = 0; s < 8; ++s) {
            bf16x8 Ah = *(const bf16x8*)(arow + s * 32);
            bf16x8 Al = *(const bf16x8*)(arow + GLDS_TILE + s * 32);
#pragma unroll
            for (int c = 0; c < 2; ++c) {
                int cp = chalf * 2 + c;
                const __bf16* wb = wpkh + (size_t)(((e * 8 + s) * 4 + cp) * 64 + lane) * 8;
                const __bf16* wbl = wpkl + (size_t)(((e * 8 + s) * 4 + cp) * 64 + lane) * 8;
                bf16x8 Bh = *(const bf16x8*)wb;
                bf16x8 Bl = *(const bf16x8*)wbl;
                acc[c] = __builtin_amdgcn_mfma_f32_32x32x16_bf16(Ah, Bh, acc[c], 0, 0, 0);
                acc[c] = __builtin_amdgcn_mfma_f32_32x32x16_bf16(Al, Bh, acc[c], 0, 0, 0);
                acc[c] = __builtin_amdgcn_mfma_f32_32x32x16_bf16(Ah, Bl, acc[c], 0, 0, 0);
            }
        }
        float gt[16];
#pragma unroll
        for (int r = 0; r < 16; ++r) {
            int rr = rowbase + (r & 3) + 8 * (r >> 2);
            gt[r] = (rr < N) ? gates[(size_t)rr * 6 + gate_off + e] : 0.f;
        }
#pragma unroll
        for (int c = 0; c < 2; ++c) {
            float bb = bias[e * HID + chalf * 64 + c * 32 + m];
#pragma unroll
            for (int r = 0; r < 16; ++r)
                F[c][r] += gt[r] * fmaxf(acc[c][r] + bb, 0.f);
        }
    }

#pragma unroll
    for (int c = 0; c < 2; ++c) {
        int colg = chalf * 64 + c * 32 + m;
#pragma unroll
        for (int r = 0; r < 16; ++r) {
            int rr = rowbase + (r & 3) + 8 * (r >> 2);
            if (rr < N) {
                if (hout32) hout32[(size_t)rr * HID + colg] = F[c][r];
                if (hout16) hout16[(size_t)rr * HID + colg] = (_Float16)F[c][r];
            }
        }
    }
}

// ---------------- pooling + final ----------------

__global__ void find_starts_kernel(const int* __restrict__ batch, int* __restrict__ gstart,
                                   int N, int G) {
    int g = blockIdx.x * blockDim.x + threadIdx.x;
    if (g > G) return;
    if (g == G) { gstart[G] = N; return; }
    int lo = 0, hi = N;
    while (lo < hi) {
        int mid = (lo + hi) >> 1;
        if (batch[mid] < g) lo = mid + 1; else hi = mid;
    }
    gstart[g] = lo;
}

__global__ __launch_bounds__(128) void pool_partial_kernel(const float* __restrict__ h,
                                                           const int* __restrict__ batch,
                                                           float* __restrict__ pooled, int N) {
    int f = threadIdx.x;
    int base = blockIdx.x * POOL_CHUNK;
    int end = min(base + POOL_CHUNK, N);
    if (base >= N) return;
    int cur = batch[base];
    float acc = 0.f;
    for (int i = base; i < end; ++i) {
        int g = batch[i];
        if (g != cur) {
            atomicAdd(&pooled[cur * HID + f], acc);
            acc = 0.f;
            cur = g;
        }
        acc += h[(size_t)i * HID + f];
    }
    atomicAdd(&pooled[cur * HID + f], acc);
}

__global__ __launch_bounds__(64) void final_kernel(const float* __restrict__ pooled,
                                                   const int* __restrict__ gstart,
                                                   const float* __restrict__ Wf,
                                                   const float* __restrict__ bf,
                                                   float* __restrict__ out) {
    __shared__ float ps[HID];
    int g = blockIdx.x;
    int o = threadIdx.x;
    float invc = 1.0f / fmaxf((float)(gstart[g + 1] - gstart[g]), 1.0f);
    ps[o] = pooled[g * HID + o] * invc;
    ps[o + 64] = pooled[g * HID + o + 64] * invc;
    __syncthreads();
    float acc = bf[o];
#pragma unroll 8
    for (int k = 0; k < HID; ++k) acc = fmaf(ps[k], Wf[k * OUTC + o], acc);
    out[g * OUTC + o] = acc;
}

// ---------------- launch ----------------

extern "C" void kernel_launch(void* const* d_in, const int* in_sizes, int n_in,
                              void* d_out, int out_size, void* d_ws, size_t ws_size,
                              hipStream_t stream) {
    const float* x   = (const float*)d_in[0];
    const float* tf  = (const float*)d_in[1];
    const int*   ei  = (const int*)d_in[2];
    const int*   bat = (const int*)d_in[3];
    const float* W0  = (const float*)d_in[4];
    const float* b0  = (const float*)d_in[5];
    const float* Wg0 = (const float*)d_in[6];
    const float* W1  = (const float*)d_in[7];
    const float* b1  = (const float*)d_in[8];
    const float* Wg1 = (const float*)d_in[9];
    const float* Wf  = (const float*)d_in[10];
    const float* bf  = (const float*)d_in[11];
    float* out = (float*)d_out;

    const int N = in_sizes[0] / HID;       // 50000
    const int E = in_sizes[2] / 2;         // 800000
    const int G = out_size / OUTC;         // 64
    const int NB = (N + 1023) / 1024;

    char* p = (char*)d_ws;
    auto alloc = [&](size_t bytes) -> void* {
        void* r = (void*)p;
        p += (bytes + 255) & ~(size_t)255;
        return r;
    };
    float*    dinv   = (float*)alloc((size_t)N * 4);
    int*      cnt    = (int*)alloc((size_t)N * 4);
    int*      rowp   = (int*)alloc((size_t)(N + 1) * 4);
    int*      cursor = (int*)alloc((size_t)N * 4);
    float*    gates  = (float*)alloc((size_t)N * 6 * 4);
    int2*     erec   = (int2*)alloc((size_t)E * 8);
    __bf16*   aghi   = (__bf16*)alloc((size_t)N * HID * 2);
    __bf16*   aglo   = (__bf16*)alloc((size_t)N * HID * 2);
    float*    h1     = (float*)alloc((size_t)N * HID * 4);
    _Float16* h16    = (_Float16*)alloc((size_t)N * HID * 2);
    int*      gstart = (int*)alloc((size_t)(G + 1) * 4);
    float*    pooled = (float*)alloc((size_t)G * HID * 4);
    int*      bsum   = (int*)alloc((size_t)NB * 4);
    int*      total  = (int*)alloc(4);
    __bf16*   wpkh0  = (__bf16*)alloc((size_t)EXP * HID * HID * 2);
    __bf16*   wpkl0  = (__bf16*)alloc((size_t)EXP * HID * HID * 2);
    __bf16*   wpkh1  = (__bf16*)alloc((size_t)EXP * HID * HID * 2);
    __bf16*   wpkl1  = (__bf16*)alloc((size_t)EXP * HID * HID * 2);

    const int* src = ei;
    const int* dst = ei + E;

    hipMemsetAsync(cnt, 0, (size_t)N * 4, stream);
    hipMemsetAsync(pooled, 0, (size_t)G * HID * 4, stream);

    count_kernel<<<(E + 255) / 256, 256, 0, stream>>>(dst, cnt, E);
    dinv_kernel<<<(N + 255) / 256, 256, 0, stream>>>(cnt, dinv, N);
    scan_local_kernel<<<NB, 256, 0, stream>>>(cnt, rowp, bsum, N);
    scan_bsum_kernel<<<1, 64, 0, stream>>>(bsum, NB, total);
    scan_fixup_kernel<<<NB, 256, 0, stream>>>(bsum, total, rowp, cursor, N);
    fill_kernel<<<((E + 255) / 256) * 8, 256, 0, stream>>>(src, dst, cursor, dinv, erec, E);
    gates_kernel<<<(N + 255) / 256, 256, 0, stream>>>(tf, Wg0, Wg1, gates, N);
    pack_w_kernel<<<192, 64, 0, stream>>>(W0, W1, wpkh0, wpkl0, wpkh1, wpkl1);
    f32_to_f16_kernel<<<(N * HID / 4 + 255) / 256, 256, 0, stream>>>(x, h16, N * HID / 4);

    int gemm_blocks = (N + 63) / 64;

    // layer 1: gather x16 -> ag; GEMM writes fp16 h only
    aggregate_kernel<<<N, 128, 0, stream>>>(h16, aghi, aglo, rowp, erec, dinv, N);
    expert_gemm_mfma_kernel<<<gemm_blocks, 256, 0, stream>>>(aghi, aglo, wpkh0, wpkl0,
                                                             b0, gates, 0, nullptr, h16, N);
    // layer 2: gather h16 -> ag; GEMM writes fp32 h (feeds pooling)
    aggregate_kernel<<<N, 128, 0, stream>>>(h16, aghi, aglo, rowp, erec, dinv, N);
    expert_gemm_mfma_kernel<<<gemm_blocks, 256, 0, stream>>>(aghi, aglo, wpkh1, wpkl1,
                                                             b1, gates, 3, h1, nullptr, N);

    // pooling + final projection
    find_starts_kernel<<<1, 128, 0, stream>>>(bat, gstart, N, G);
    pool_partial_kernel<<<(N + POOL_CHUNK - 1) / POOL_CHUNK, 128, 0, stream>>>(h1, bat, pooled, N);
    final_kernel<<<G, 64, 0, stream>>>(pooled, gstart, Wf, bf, out);
}

// Round 8
// 410.341 us; speedup vs baseline: 1.0249x; 1.0249x over previous
//
#include <hip/hip_runtime.h>
#include <hip/hip_bf16.h>

#define HID 128
#define EXP 3
#define TOP 4
#define OUTC 64
#define POOL_CHUNK 128

typedef __bf16 bf16x8 __attribute__((ext_vector_type(8)));
typedef float f32x16 __attribute__((ext_vector_type(16)));
typedef _Float16 half4 __attribute__((ext_vector_type(4)));

#define GLDS_STRIDE 272              // 128 bf16 = 256B + 16B pad
#define GLDS_TILE (64 * GLDS_STRIDE) // 17408 B (single bf16 tile)

// ---------------- CSR build ----------------

__global__ void count_kernel(const int* __restrict__ dst, int* __restrict__ cnt, int E) {
    int i = blockIdx.x * blockDim.x + threadIdx.x;
    if (i < E) atomicAdd(&cnt[dst[i]], 1);
}

__global__ void dinv_kernel(const int* __restrict__ cnt, float* __restrict__ dinv, int N) {
    int n = blockIdx.x * blockDim.x + threadIdx.x;
    if (n < N) dinv[n] = rsqrtf((float)cnt[n] + 1.0f);
}

// ---------------- hierarchical scan ----------------

__global__ __launch_bounds__(256) void scan_local_kernel(const int* __restrict__ cnt,
                                                         int* __restrict__ row_ptr,
                                                         int* __restrict__ bsum, int N) {
    __shared__ int sh[256];
    int b = blockIdx.x;
    int t = threadIdx.x;
    int base = b * 1024 + t * 4;
    int v[4] = {0, 0, 0, 0};
    if (base + 3 < N) {
        int4 c = *(const int4*)(cnt + base);
        v[0] = c.x; v[1] = c.y; v[2] = c.z; v[3] = c.w;
    } else {
#pragma unroll
        for (int k = 0; k < 4; ++k) if (base + k < N) v[k] = cnt[base + k];
    }
    int s = v[0] + v[1] + v[2] + v[3];
    sh[t] = s;
    __syncthreads();
    for (int off = 1; off < 256; off <<= 1) {
        int u = (t >= off) ? sh[t - off] : 0;
        __syncthreads();
        sh[t] += u;
        __syncthreads();
    }
    int run = sh[t] - s;
#pragma unroll
    for (int k = 0; k < 4; ++k) {
        if (base + k < N) row_ptr[base + k] = run;
        run += v[k];
    }
    if (t == 255) bsum[b] = sh[255];
}

__global__ __launch_bounds__(64) void scan_bsum_kernel(int* __restrict__ bsum, int nb,
                                                       int* __restrict__ total) {
    int t = threadIdx.x;
    int carry = 0;
    for (int base = 0; base < nb; base += 64) {
        int i = base + t;
        int v = (i < nb) ? bsum[i] : 0;
        int s = v;
#pragma unroll
        for (int off = 1; off < 64; off <<= 1) {
            int u = __shfl_up(s, off, 64);
            if (t >= off) s += u;
        }
        if (i < nb) bsum[i] = s - v + carry;
        carry += __shfl(s, 63, 64);
    }
    if (t == 0) *total = carry;
}

__global__ __launch_bounds__(256) void scan_fixup_kernel(const int* __restrict__ bsum,
                                                         const int* __restrict__ total,
                                                         int* __restrict__ row_ptr,
                                                         int* __restrict__ cursor, int N) {
    int b = blockIdx.x;
    int t = threadIdx.x;
    int off = bsum[b];
    int base = b * 1024 + t * 4;
#pragma unroll
    for (int k = 0; k < 4; ++k) {
        int i = base + k;
        if (i < N) {
            int r = row_ptr[i] + off;
            row_ptr[i] = r;
            cursor[i] = r;
        }
    }
    if (b == 0 && t == 0) row_ptr[N] = *total;
}

// XCD-sliced fill (keeps a node's CSR line owned by one slice of blocks)
__global__ void fill_kernel(const int* __restrict__ src, const int* __restrict__ dst,
                            int* __restrict__ cursor, const float* __restrict__ dinv,
                            int2* __restrict__ erec, int E) {
    int slice = blockIdx.x & 7;
    int i = (blockIdx.x >> 3) * blockDim.x + threadIdx.x;
    if (i >= E) return;
    int d = dst[i];
    if (((d >> 6) & 7) != slice) return;
    int s = src[i];
    int p = atomicAdd(&cursor[d], 1);
    erec[p] = make_int2(s, __float_as_int(dinv[s] * dinv[d]));
}

// ---------------- gates ----------------

__global__ void gates_kernel(const float* __restrict__ tf, const float* __restrict__ Wg0,
                             const float* __restrict__ Wg1, float* __restrict__ gates, int N) {
    int n = blockIdx.x * blockDim.x + threadIdx.x;
    if (n >= N) return;
    float4 t = *(const float4*)(tf + (size_t)n * TOP);
    const float* Wg[2] = {Wg0, Wg1};
#pragma unroll
    for (int l = 0; l < 2; ++l) {
        float lg[EXP];
#pragma unroll
        for (int e = 0; e < EXP; ++e) {
            const float* w = Wg[l] + e * TOP;
            lg[e] = (t.x * w[0] + t.y * w[1] + t.z * w[2] + t.w * w[3]) * (1.0f / 101.0f);
        }
        float m = fmaxf(lg[0], fmaxf(lg[1], lg[2]));
        float e0 = expf(lg[0] - m), e1 = expf(lg[1] - m), e2 = expf(lg[2] - m);
        float inv = 1.0f / (e0 + e1 + e2);
        gates[n * 6 + l * 3 + 0] = e0 * inv;
        gates[n * 6 + l * 3 + 1] = e1 * inv;
        gates[n * 6 + l * 3 + 2] = e2 * inv;
    }
}

// ---------------- fp32 -> fp16 shadow ----------------

__global__ void f32_to_f16_kernel(const float* __restrict__ x, _Float16* __restrict__ y,
                                  int total4) {
    int i = blockIdx.x * blockDim.x + threadIdx.x;
    if (i >= total4) return;
    float4 v = ((const float4*)x)[i];
    half4 h = {(_Float16)v.x, (_Float16)v.y, (_Float16)v.z, (_Float16)v.w};
    ((half4*)y)[i] = h;
}

// ---------------- W pack: B-fragment lane order, single bf16 ----------------

__global__ __launch_bounds__(64) void pack_w_kernel(const float* __restrict__ W0,
                                                    const float* __restrict__ W1,
                                                    __bf16* __restrict__ ph0,
                                                    __bf16* __restrict__ ph1) {
    int bid = blockIdx.x;           // 0..191
    int layer = bid / 96;
    int rem = bid % 96;
    int e = rem / 32;
    int s = (rem % 32) / 4;
    int c = rem % 4;
    const float* W = layer ? W1 : W0;
    __bf16* ph = layer ? ph1 : ph0;
    int l = threadIdx.x;
    size_t dstbase = (size_t)((((e * 8 + s) * 4 + c) * 64 + l)) * 8;
    int kbase = s * 16 + (l >> 5) * 8;
    int n = c * 32 + (l & 31);
#pragma unroll
    for (int j = 0; j < 8; ++j) {
        float w = W[(size_t)e * (HID * HID) + (size_t)(kbase + j) * HID + n];
        ph[dstbase + j] = (__bf16)w;
    }
}

// ---------------- aggregation: ag = A_hat @ h16, output single bf16 ----------------

__global__ __launch_bounds__(128) void aggregate_kernel(const _Float16* __restrict__ h16,
                                                        __bf16* __restrict__ aghi,
                                                        const int* __restrict__ row_ptr,
                                                        const int2* __restrict__ erec,
                                                        const float* __restrict__ dinv, int N) {
    __shared__ float red[2][HID];
    int n = blockIdx.x;
    int t = threadIdx.x;
    int c4 = t & 31;
    int es = t >> 5;
    int s = row_ptr[n], e = row_ptr[n + 1];

    float4 acc = make_float4(0.f, 0.f, 0.f, 0.f);
    int i = s + es;
    for (; i + 4 < e; i += 8) {
        int2 r0 = erec[i], r1 = erec[i + 4];
        float w0 = __int_as_float(r0.y), w1 = __int_as_float(r1.y);
        half4 v0 = *(const half4*)(h16 + (size_t)r0.x * HID + c4 * 4);
        half4 v1 = *(const half4*)(h16 + (size_t)r1.x * HID + c4 * 4);
        acc.x += (float)v0.x * w0 + (float)v1.x * w1;
        acc.y += (float)v0.y * w0 + (float)v1.y * w1;
        acc.z += (float)v0.z * w0 + (float)v1.z * w1;
        acc.w += (float)v0.w * w0 + (float)v1.w * w1;
    }
    if (i < e) {
        int2 r0 = erec[i];
        float w0 = __int_as_float(r0.y);
        half4 v0 = *(const half4*)(h16 + (size_t)r0.x * HID + c4 * 4);
        acc.x += (float)v0.x * w0; acc.y += (float)v0.y * w0;
        acc.z += (float)v0.z * w0; acc.w += (float)v0.w * w0;
    }

    acc.x += __shfl_xor(acc.x, 32, 64);
    acc.y += __shfl_xor(acc.y, 32, 64);
    acc.z += __shfl_xor(acc.z, 32, 64);
    acc.w += __shfl_xor(acc.w, 32, 64);
    int wv = t >> 6;
    int lane = t & 63;
    if (lane < 32) *(float4*)(&red[wv][lane * 4]) = acc;
    __syncthreads();

    float dn = dinv[n];
    float a = red[0][t] + red[1][t] + (float)h16[(size_t)n * HID + t] * dn * dn;
    aghi[(size_t)n * HID + t] = (__bf16)a;
}

// ---------------- MFMA fused 3-expert GEMM + relu + gate (single-pass bf16) ----------------
// 64-row tile / block; 4 waves: wave w -> rows 32*(w&1), cols 64*(w>>1).
// 17 KB LDS, ~64 acc VGPRs.

__global__ __launch_bounds__(256, 4) void expert_gemm_mfma_kernel(
        const __bf16* __restrict__ aghi,
        const __bf16* __restrict__ wpkh,
        const float* __restrict__ bias, const float* __restrict__ gates, int gate_off,
        float* __restrict__ hout32, _Float16* __restrict__ hout16, int N) {
    __shared__ char lds[GLDS_TILE];
    int tid = threadIdx.x;
    int row0 = blockIdx.x * 64;

    // stage 64 rows: 1024 16B-chunks
#pragma unroll
    for (int it = 0; it < 4; ++it) {
        int id = tid + it * 256;
        int r = id >> 4;
        int c = id & 15;
        int gr = row0 + r;
        float4 vh = make_float4(0.f, 0.f, 0.f, 0.f);
        if (gr < N) vh = ((const float4*)aghi)[(size_t)gr * 16 + c];
        *(float4*)(lds + r * GLDS_STRIDE + c * 16) = vh;
    }
    __syncthreads();

    int lane = tid & 63;
    int wave = tid >> 6;
    int m = lane & 31;
    int g = lane >> 5;
    int rhalf = wave & 1;
    int chalf = wave >> 1;
    const char* arow = lds + (rhalf * 32 + m) * GLDS_STRIDE + g * 16;
    int rowbase = row0 + rhalf * 32 + 4 * g;

    float F[2][16];
#pragma unroll
    for (int c = 0; c < 2; ++c)
#pragma unroll
        for (int r = 0; r < 16; ++r) F[c][r] = 0.f;

    for (int e = 0; e < EXP; ++e) {
        f32x16 acc[2];
#pragma unroll
        for (int c = 0; c < 2; ++c)
#pragma unroll
            for (int r = 0; r < 16; ++r) acc[c][r] = 0.f;

#pragma unroll
        for (int s = 0; s < 8; ++s) {
            bf16x8 Ah = *(const bf16x8*)(arow + s * 32);
#pragma unroll
            for (int c = 0; c < 2; ++c) {
                int cp = chalf * 2 + c;
                bf16x8 Bh = *(const bf16x8*)(wpkh + (size_t)(((e * 8 + s) * 4 + cp) * 64 + lane) * 8);
                acc[c] = __builtin_amdgcn_mfma_f32_32x32x16_bf16(Ah, Bh, acc[c], 0, 0, 0);
            }
        }
        float gt[16];
#pragma unroll
        for (int r = 0; r < 16; ++r) {
            int rr = rowbase + (r & 3) + 8 * (r >> 2);
            gt[r] = (rr < N) ? gates[(size_t)rr * 6 + gate_off + e] : 0.f;
        }
#pragma unroll
        for (int c = 0; c < 2; ++c) {
            float bb = bias[e * HID + chalf * 64 + c * 32 + m];
#pragma unroll
            for (int r = 0; r < 16; ++r)
                F[c][r] += gt[r] * fmaxf(acc[c][r] + bb, 0.f);
        }
    }

#pragma unroll
    for (int c = 0; c < 2; ++c) {
        int colg = chalf * 64 + c * 32 + m;
#pragma unroll
        for (int r = 0; r < 16; ++r) {
            int rr = rowbase + (r & 3) + 8 * (r >> 2);
            if (rr < N) {
                if (hout32) hout32[(size_t)rr * HID + colg] = F[c][r];
                if (hout16) hout16[(size_t)rr * HID + colg] = (_Float16)F[c][r];
            }
        }
    }
}

// ---------------- pooling + final ----------------

__global__ void find_starts_kernel(const int* __restrict__ batch, int* __restrict__ gstart,
                                   int N, int G) {
    int g = blockIdx.x * blockDim.x + threadIdx.x;
    if (g > G) return;
    if (g == G) { gstart[G] = N; return; }
    int lo = 0, hi = N;
    while (lo < hi) {
        int mid = (lo + hi) >> 1;
        if (batch[mid] < g) lo = mid + 1; else hi = mid;
    }
    gstart[g] = lo;
}

__global__ __launch_bounds__(128) void pool_partial_kernel(const float* __restrict__ h,
                                                           const int* __restrict__ batch,
                                                           float* __restrict__ pooled, int N) {
    int f = threadIdx.x;
    int base = blockIdx.x * POOL_CHUNK;
    int end = min(base + POOL_CHUNK, N);
    if (base >= N) return;
    int cur = batch[base];
    float acc = 0.f;
    for (int i = base; i < end; ++i) {
        int g = batch[i];
        if (g != cur) {
            atomicAdd(&pooled[cur * HID + f], acc);
            acc = 0.f;
            cur = g;
        }
        acc += h[(size_t)i * HID + f];
    }
    atomicAdd(&pooled[cur * HID + f], acc);
}

__global__ __launch_bounds__(64) void final_kernel(const float* __restrict__ pooled,
                                                   const int* __restrict__ gstart,
                                                   const float* __restrict__ Wf,
                                                   const float* __restrict__ bf,
                                                   float* __restrict__ out) {
    __shared__ float ps[HID];
    int g = blockIdx.x;
    int o = threadIdx.x;
    float invc = 1.0f / fmaxf((float)(gstart[g + 1] - gstart[g]), 1.0f);
    ps[o] = pooled[g * HID + o] * invc;
    ps[o + 64] = pooled[g * HID + o + 64] * invc;
    __syncthreads();
    float acc = bf[o];
#pragma unroll 8
    for (int k = 0; k < HID; ++k) acc = fmaf(ps[k], Wf[k * OUTC + o], acc);
    out[g * OUTC + o] = acc;
}

// ---------------- launch ----------------

extern "C" void kernel_launch(void* const* d_in, const int* in_sizes, int n_in,
                              void* d_out, int out_size, void* d_ws, size_t ws_size,
                              hipStream_t stream) {
    const float* x   = (const float*)d_in[0];
    const float* tf  = (const float*)d_in[1];
    const int*   ei  = (const int*)d_in[2];
    const int*   bat = (const int*)d_in[3];
    const float* W0  = (const float*)d_in[4];
    const float* b0  = (const float*)d_in[5];
    const float* Wg0 = (const float*)d_in[6];
    const float* W1  = (const float*)d_in[7];
    const float* b1  = (const float*)d_in[8];
    const float* Wg1 = (const float*)d_in[9];
    const float* Wf  = (const float*)d_in[10];
    const float* bf  = (const float*)d_in[11];
    float* out = (float*)d_out;

    const int N = in_sizes[0] / HID;       // 50000
    const int E = in_sizes[2] / 2;         // 800000
    const int G = out_size / OUTC;         // 64
    const int NB = (N + 1023) / 1024;

    char* p = (char*)d_ws;
    auto alloc = [&](size_t bytes) -> void* {
        void* r = (void*)p;
        p += (bytes + 255) & ~(size_t)255;
        return r;
    };
    float*    dinv   = (float*)alloc((size_t)N * 4);
    int*      cnt    = (int*)alloc((size_t)N * 4);
    int*      rowp   = (int*)alloc((size_t)(N + 1) * 4);
    int*      cursor = (int*)alloc((size_t)N * 4);
    float*    gates  = (float*)alloc((size_t)N * 6 * 4);
    int2*     erec   = (int2*)alloc((size_t)E * 8);
    __bf16*   aghi   = (__bf16*)alloc((size_t)N * HID * 2);
    float*    h1     = (float*)alloc((size_t)N * HID * 4);
    _Float16* h16    = (_Float16*)alloc((size_t)N * HID * 2);
    int*      gstart = (int*)alloc((size_t)(G + 1) * 4);
    float*    pooled = (float*)alloc((size_t)G * HID * 4);
    int*      bsum   = (int*)alloc((size_t)NB * 4);
    int*      total  = (int*)alloc(4);
    __bf16*   wpkh0  = (__bf16*)alloc((size_t)EXP * HID * HID * 2);
    __bf16*   wpkh1  = (__bf16*)alloc((size_t)EXP * HID * HID * 2);

    const int* src = ei;
    const int* dst = ei + E;

    hipMemsetAsync(cnt, 0, (size_t)N * 4, stream);
    hipMemsetAsync(pooled, 0, (size_t)G * HID * 4, stream);

    count_kernel<<<(E + 255) / 256, 256, 0, stream>>>(dst, cnt, E);
    dinv_kernel<<<(N + 255) / 256, 256, 0, stream>>>(cnt, dinv, N);
    scan_local_kernel<<<NB, 256, 0, stream>>>(cnt, rowp, bsum, N);
    scan_bsum_kernel<<<1, 64, 0, stream>>>(bsum, NB, total);
    scan_fixup_kernel<<<NB, 256, 0, stream>>>(bsum, total, rowp, cursor, N);
    fill_kernel<<<((E + 255) / 256) * 8, 256, 0, stream>>>(src, dst, cursor, dinv, erec, E);
    gates_kernel<<<(N + 255) / 256, 256, 0, stream>>>(tf, Wg0, Wg1, gates, N);
    pack_w_kernel<<<192, 64, 0, stream>>>(W0, W1, wpkh0, wpkh1);
    f32_to_f16_kernel<<<(N * HID / 4 + 255) / 256, 256, 0, stream>>>(x, h16, N * HID / 4);

    int gemm_blocks = (N + 63) / 64;

    // layer 1: gather x16 -> ag; GEMM writes fp16 h only
    aggregate_kernel<<<N, 128, 0, stream>>>(h16, aghi, rowp, erec, dinv, N);
    expert_gemm_mfma_kernel<<<gemm_blocks, 256, 0, stream>>>(aghi, wpkh0,
                                                             b0, gates, 0, nullptr, h16, N);
    // layer 2: gather h16 -> ag; GEMM writes fp32 h (feeds pooling)
    aggregate_kernel<<<N, 128, 0, stream>>>(h16, aghi, rowp, erec, dinv, N);
    expert_gemm_mfma_kernel<<<gemm_blocks, 256, 0, stream>>>(aghi, wpkh1,
                                                             b1, gates, 3, h1, nullptr, N);

    // pooling + final projection
    find_starts_kernel<<<1, 128, 0, stream>>>(bat, gstart, N, G);
    pool_partial_kernel<<<(N + POOL_CHUNK - 1) / POOL_CHUNK, 128, 0, stream>>>(h1, bat, pooled, N);
    final_kernel<<<G, 64, 0, stream>>>(pooled, gstart, Wf, bf, out);
}

// Round 9
// 379.804 us; speedup vs baseline: 1.1073x; 1.0804x over previous
//
#include <hip/hip_runtime.h>
#include <hip/hip_bf16.h>

#define HID 128
#define EXP 3
#define TOP 4
#define OUTC 64
#define POOL_CHUNK 128

typedef __bf16 bf16x8 __attribute__((ext_vector_type(8)));
typedef float f32x16 __attribute__((ext_vector_type(16)));
typedef _Float16 half4 __attribute__((ext_vector_type(4)));

#define GLDS_STRIDE 272              // staging: 128 bf16 = 256B + 16B pad
#define OUT_STRIDE 132               // out tile: 128 fp32 + 4 pad dwords (528B rows)

// ---------------- CSR build ----------------

__global__ void count_kernel(const int* __restrict__ dst, int* __restrict__ cnt, int E) {
    int i = blockIdx.x * blockDim.x + threadIdx.x;
    if (i < E) atomicAdd(&cnt[dst[i]], 1);
}

__global__ void dinv_kernel(const int* __restrict__ cnt, float* __restrict__ dinv, int N) {
    int n = blockIdx.x * blockDim.x + threadIdx.x;
    if (n < N) dinv[n] = rsqrtf((float)cnt[n] + 1.0f);
}

// ---------------- hierarchical scan ----------------

__global__ __launch_bounds__(256) void scan_local_kernel(const int* __restrict__ cnt,
                                                         int* __restrict__ row_ptr,
                                                         int* __restrict__ bsum, int N) {
    __shared__ int sh[256];
    int b = blockIdx.x;
    int t = threadIdx.x;
    int base = b * 1024 + t * 4;
    int v[4] = {0, 0, 0, 0};
    if (base + 3 < N) {
        int4 c = *(const int4*)(cnt + base);
        v[0] = c.x; v[1] = c.y; v[2] = c.z; v[3] = c.w;
    } else {
#pragma unroll
        for (int k = 0; k < 4; ++k) if (base + k < N) v[k] = cnt[base + k];
    }
    int s = v[0] + v[1] + v[2] + v[3];
    sh[t] = s;
    __syncthreads();
    for (int off = 1; off < 256; off <<= 1) {
        int u = (t >= off) ? sh[t - off] : 0;
        __syncthreads();
        sh[t] += u;
        __syncthreads();
    }
    int run = sh[t] - s;
#pragma unroll
    for (int k = 0; k < 4; ++k) {
        if (base + k < N) row_ptr[base + k] = run;
        run += v[k];
    }
    if (t == 255) bsum[b] = sh[255];
}

__global__ __launch_bounds__(64) void scan_bsum_kernel(int* __restrict__ bsum, int nb,
                                                       int* __restrict__ total) {
    int t = threadIdx.x;
    int carry = 0;
    for (int base = 0; base < nb; base += 64) {
        int i = base + t;
        int v = (i < nb) ? bsum[i] : 0;
        int s = v;
#pragma unroll
        for (int off = 1; off < 64; off <<= 1) {
            int u = __shfl_up(s, off, 64);
            if (t >= off) s += u;
        }
        if (i < nb) bsum[i] = s - v + carry;
        carry += __shfl(s, 63, 64);
    }
    if (t == 0) *total = carry;
}

__global__ __launch_bounds__(256) void scan_fixup_kernel(const int* __restrict__ bsum,
                                                         const int* __restrict__ total,
                                                         int* __restrict__ row_ptr,
                                                         int* __restrict__ cursor, int N) {
    int b = blockIdx.x;
    int t = threadIdx.x;
    int off = bsum[b];
    int base = b * 1024 + t * 4;
#pragma unroll
    for (int k = 0; k < 4; ++k) {
        int i = base + k;
        if (i < N) {
            int r = row_ptr[i] + off;
            row_ptr[i] = r;
            cursor[i] = r;
        }
    }
    if (b == 0 && t == 0) row_ptr[N] = *total;
}

// XCD-sliced fill (keeps a node's CSR line owned by one slice of blocks)
__global__ void fill_kernel(const int* __restrict__ src, const int* __restrict__ dst,
                            int* __restrict__ cursor, const float* __restrict__ dinv,
                            int2* __restrict__ erec, int E) {
    int slice = blockIdx.x & 7;
    int i = (blockIdx.x >> 3) * blockDim.x + threadIdx.x;
    if (i >= E) return;
    int d = dst[i];
    if (((d >> 6) & 7) != slice) return;
    int s = src[i];
    int p = atomicAdd(&cursor[d], 1);
    erec[p] = make_int2(s, __float_as_int(dinv[s] * dinv[d]));
}

// ---------------- gates ----------------

__global__ void gates_kernel(const float* __restrict__ tf, const float* __restrict__ Wg0,
                             const float* __restrict__ Wg1, float* __restrict__ gates, int N) {
    int n = blockIdx.x * blockDim.x + threadIdx.x;
    if (n >= N) return;
    float4 t = *(const float4*)(tf + (size_t)n * TOP);
    const float* Wg[2] = {Wg0, Wg1};
#pragma unroll
    for (int l = 0; l < 2; ++l) {
        float lg[EXP];
#pragma unroll
        for (int e = 0; e < EXP; ++e) {
            const float* w = Wg[l] + e * TOP;
            lg[e] = (t.x * w[0] + t.y * w[1] + t.z * w[2] + t.w * w[3]) * (1.0f / 101.0f);
        }
        float m = fmaxf(lg[0], fmaxf(lg[1], lg[2]));
        float e0 = expf(lg[0] - m), e1 = expf(lg[1] - m), e2 = expf(lg[2] - m);
        float inv = 1.0f / (e0 + e1 + e2);
        gates[n * 6 + l * 3 + 0] = e0 * inv;
        gates[n * 6 + l * 3 + 1] = e1 * inv;
        gates[n * 6 + l * 3 + 2] = e2 * inv;
    }
}

// ---------------- fp32 -> fp16 shadow ----------------

__global__ void f32_to_f16_kernel(const float* __restrict__ x, _Float16* __restrict__ y,
                                  int total4) {
    int i = blockIdx.x * blockDim.x + threadIdx.x;
    if (i >= total4) return;
    float4 v = ((const float4*)x)[i];
    half4 h = {(_Float16)v.x, (_Float16)v.y, (_Float16)v.z, (_Float16)v.w};
    ((half4*)y)[i] = h;
}

// ---------------- W pack: B-fragment lane order, single bf16 ----------------

__global__ __launch_bounds__(64) void pack_w_kernel(const float* __restrict__ W0,
                                                    const float* __restrict__ W1,
                                                    __bf16* __restrict__ ph0,
                                                    __bf16* __restrict__ ph1) {
    int bid = blockIdx.x;           // 0..191
    int layer = bid / 96;
    int rem = bid % 96;
    int e = rem / 32;
    int s = (rem % 32) / 4;
    int c = rem % 4;
    const float* W = layer ? W1 : W0;
    __bf16* ph = layer ? ph1 : ph0;
    int l = threadIdx.x;
    size_t dstbase = (size_t)((((e * 8 + s) * 4 + c) * 64 + l)) * 8;
    int kbase = s * 16 + (l >> 5) * 8;
    int n = c * 32 + (l & 31);
#pragma unroll
    for (int j = 0; j < 8; ++j) {
        float w = W[(size_t)e * (HID * HID) + (size_t)(kbase + j) * HID + n];
        ph[dstbase + j] = (__bf16)w;
    }
}

// ---------------- aggregation: ag = A_hat @ h16, output single bf16 ----------------

__global__ __launch_bounds__(128) void aggregate_kernel(const _Float16* __restrict__ h16,
                                                        __bf16* __restrict__ aghi,
                                                        const int* __restrict__ row_ptr,
                                                        const int2* __restrict__ erec,
                                                        const float* __restrict__ dinv, int N) {
    __shared__ float red[2][HID];
    int n = blockIdx.x;
    int t = threadIdx.x;
    int c4 = t & 31;
    int es = t >> 5;
    int s = row_ptr[n], e = row_ptr[n + 1];

    float4 acc = make_float4(0.f, 0.f, 0.f, 0.f);
    int i = s + es;
    for (; i + 4 < e; i += 8) {
        int2 r0 = erec[i], r1 = erec[i + 4];
        float w0 = __int_as_float(r0.y), w1 = __int_as_float(r1.y);
        half4 v0 = *(const half4*)(h16 + (size_t)r0.x * HID + c4 * 4);
        half4 v1 = *(const half4*)(h16 + (size_t)r1.x * HID + c4 * 4);
        acc.x += (float)v0.x * w0 + (float)v1.x * w1;
        acc.y += (float)v0.y * w0 + (float)v1.y * w1;
        acc.z += (float)v0.z * w0 + (float)v1.z * w1;
        acc.w += (float)v0.w * w0 + (float)v1.w * w1;
    }
    if (i < e) {
        int2 r0 = erec[i];
        float w0 = __int_as_float(r0.y);
        half4 v0 = *(const half4*)(h16 + (size_t)r0.x * HID + c4 * 4);
        acc.x += (float)v0.x * w0; acc.y += (float)v0.y * w0;
        acc.z += (float)v0.z * w0; acc.w += (float)v0.w * w0;
    }

    acc.x += __shfl_xor(acc.x, 32, 64);
    acc.y += __shfl_xor(acc.y, 32, 64);
    acc.z += __shfl_xor(acc.z, 32, 64);
    acc.w += __shfl_xor(acc.w, 32, 64);
    int wv = t >> 6;
    int lane = t & 63;
    if (lane < 32) *(float4*)(&red[wv][lane * 4]) = acc;
    __syncthreads();

    float dn = dinv[n];
    float a = red[0][t] + red[1][t] + (float)h16[(size_t)n * HID + t] * dn * dn;
    aghi[(size_t)n * HID + t] = (__bf16)a;
}

// ---------------- MFMA fused 3-expert GEMM + relu + gate (single-pass bf16) ----------------
// 64-row tile / block; 4 waves: wave w -> rows 32*(w&1), cols 64*(w>>1).
// Epilogue routes the C-tile through LDS so global stores are linear
// full-granule streams (1KB/instr fp32, 512B/instr fp16) -- kills the RMW
// fetch/write amplification seen in r8 (FETCH 47MB / WRITE 65MB at 19MB payload).

__global__ __launch_bounds__(256, 4) void expert_gemm_mfma_kernel(
        const __bf16* __restrict__ aghi,
        const __bf16* __restrict__ wpkh,
        const float* __restrict__ bias, const float* __restrict__ gates, int gate_off,
        float* __restrict__ hout32, _Float16* __restrict__ hout16, int N) {
    __shared__ char lds[64 * OUT_STRIDE * 4];   // 33792 B; staging uses first 17408
    int tid = threadIdx.x;
    int row0 = blockIdx.x * 64;

    // stage 64 rows of bf16 A: 1024 16B-chunks
#pragma unroll
    for (int it = 0; it < 4; ++it) {
        int id = tid + it * 256;
        int r = id >> 4;
        int c = id & 15;
        int gr = row0 + r;
        float4 vh = make_float4(0.f, 0.f, 0.f, 0.f);
        if (gr < N) vh = ((const float4*)aghi)[(size_t)gr * 16 + c];
        *(float4*)(lds + r * GLDS_STRIDE + c * 16) = vh;
    }
    __syncthreads();

    int lane = tid & 63;
    int wave = tid >> 6;
    int m = lane & 31;
    int g = lane >> 5;
    int rhalf = wave & 1;
    int chalf = wave >> 1;
    const char* arow = lds + (rhalf * 32 + m) * GLDS_STRIDE + g * 16;
    int rowbase = row0 + rhalf * 32 + 4 * g;

    float F[2][16];
#pragma unroll
    for (int c = 0; c < 2; ++c)
#pragma unroll
        for (int r = 0; r < 16; ++r) F[c][r] = 0.f;

    for (int e = 0; e < EXP; ++e) {
        f32x16 acc[2];
#pragma unroll
        for (int c = 0; c < 2; ++c)
#pragma unroll
            for (int r = 0; r < 16; ++r) acc[c][r] = 0.f;

#pragma unroll
        for (int s = 0; s < 8; ++s) {
            bf16x8 Ah = *(const bf16x8*)(arow + s * 32);
#pragma unroll
            for (int c = 0; c < 2; ++c) {
                int cp = chalf * 2 + c;
                bf16x8 Bh = *(const bf16x8*)(wpkh + (size_t)(((e * 8 + s) * 4 + cp) * 64 + lane) * 8);
                acc[c] = __builtin_amdgcn_mfma_f32_32x32x16_bf16(Ah, Bh, acc[c], 0, 0, 0);
            }
        }
        float gt[16];
#pragma unroll
        for (int r = 0; r < 16; ++r) {
            int rr = rowbase + (r & 3) + 8 * (r >> 2);
            gt[r] = (rr < N) ? gates[(size_t)rr * 6 + gate_off + e] : 0.f;
        }
#pragma unroll
        for (int c = 0; c < 2; ++c) {
            float bb = bias[e * HID + chalf * 64 + c * 32 + m];
#pragma unroll
            for (int r = 0; r < 16; ++r)
                F[c][r] += gt[r] * fmaxf(acc[c][r] + bb, 0.f);
        }
    }

    // ---- epilogue: fragments -> LDS tile -> linear streaming stores ----
    __syncthreads();            // all waves done reading A tile; reuse LDS
    float* lds32 = (float*)lds;
#pragma unroll
    for (int c = 0; c < 2; ++c) {
        int colg = chalf * 64 + c * 32 + m;
#pragma unroll
        for (int r = 0; r < 16; ++r) {
            int lr = rhalf * 32 + 4 * g + (r & 3) + 8 * (r >> 2);
            lds32[lr * OUT_STRIDE + colg] = F[c][r];
        }
    }
    __syncthreads();

    if (hout32) {
#pragma unroll
        for (int it = 0; it < 8; ++it) {
            int id = tid + it * 256;        // 2048 float4 slots
            int r = id >> 5;
            int c4 = id & 31;
            int gr = row0 + r;
            if (gr < N) {
                float4 v = *(const float4*)(&lds32[r * OUT_STRIDE + c4 * 4]);
                *(float4*)(hout32 + (size_t)gr * HID + c4 * 4) = v;
            }
        }
    }
    if (hout16) {
#pragma unroll
        for (int it = 0; it < 8; ++it) {
            int id = tid + it * 256;
            int r = id >> 5;
            int c4 = id & 31;
            int gr = row0 + r;
            if (gr < N) {
                const float* src = &lds32[r * OUT_STRIDE + c4 * 4];
                half4 v = {(_Float16)src[0], (_Float16)src[1],
                           (_Float16)src[2], (_Float16)src[3]};
                *(half4*)(hout16 + (size_t)gr * HID + c4 * 4) = v;
            }
        }
    }
}

// ---------------- pooling + final ----------------

__global__ void find_starts_kernel(const int* __restrict__ batch, int* __restrict__ gstart,
                                   int N, int G) {
    int g = blockIdx.x * blockDim.x + threadIdx.x;
    if (g > G) return;
    if (g == G) { gstart[G] = N; return; }
    int lo = 0, hi = N;
    while (lo < hi) {
        int mid = (lo + hi) >> 1;
        if (batch[mid] < g) lo = mid + 1; else hi = mid;
    }
    gstart[g] = lo;
}

__global__ __launch_bounds__(128) void pool_partial_kernel(const float* __restrict__ h,
                                                           const int* __restrict__ batch,
                                                           float* __restrict__ pooled, int N) {
    int f = threadIdx.x;
    int base = blockIdx.x * POOL_CHUNK;
    int end = min(base + POOL_CHUNK, N);
    if (base >= N) return;
    int cur = batch[base];
    float acc = 0.f;
    for (int i = base; i < end; ++i) {
        int g = batch[i];
        if (g != cur) {
            atomicAdd(&pooled[cur * HID + f], acc);
            acc = 0.f;
            cur = g;
        }
        acc += h[(size_t)i * HID + f];
    }
    atomicAdd(&pooled[cur * HID + f], acc);
}

__global__ __launch_bounds__(64) void final_kernel(const float* __restrict__ pooled,
                                                   const int* __restrict__ gstart,
                                                   const float* __restrict__ Wf,
                                                   const float* __restrict__ bf,
                                                   float* __restrict__ out) {
    __shared__ float ps[HID];
    int g = blockIdx.x;
    int o = threadIdx.x;
    float invc = 1.0f / fmaxf((float)(gstart[g + 1] - gstart[g]), 1.0f);
    ps[o] = pooled[g * HID + o] * invc;
    ps[o + 64] = pooled[g * HID + o + 64] * invc;
    __syncthreads();
    float acc = bf[o];
#pragma unroll 8
    for (int k = 0; k < HID; ++k) acc = fmaf(ps[k], Wf[k * OUTC + o], acc);
    out[g * OUTC + o] = acc;
}

// ---------------- launch ----------------

extern "C" void kernel_launch(void* const* d_in, const int* in_sizes, int n_in,
                              void* d_out, int out_size, void* d_ws, size_t ws_size,
                              hipStream_t stream) {
    const float* x   = (const float*)d_in[0];
    const float* tf  = (const float*)d_in[1];
    const int*   ei  = (const int*)d_in[2];
    const int*   bat = (const int*)d_in[3];
    const float* W0  = (const float*)d_in[4];
    const float* b0  = (const float*)d_in[5];
    const float* Wg0 = (const float*)d_in[6];
    const float* W1  = (const float*)d_in[7];
    const float* b1  = (const float*)d_in[8];
    const float* Wg1 = (const float*)d_in[9];
    const float* Wf  = (const float*)d_in[10];
    const float* bf  = (const float*)d_in[11];
    float* out = (float*)d_out;

    const int N = in_sizes[0] / HID;       // 50000
    const int E = in_sizes[2] / 2;         // 800000
    const int G = out_size / OUTC;         // 64
    const int NB = (N + 1023) / 1024;

    char* p = (char*)d_ws;
    auto alloc = [&](size_t bytes) -> void* {
        void* r = (void*)p;
        p += (bytes + 255) & ~(size_t)255;
        return r;
    };
    float*    dinv   = (float*)alloc((size_t)N * 4);
    int*      cnt    = (int*)alloc((size_t)N * 4);
    int*      rowp   = (int*)alloc((size_t)(N + 1) * 4);
    int*      cursor = (int*)alloc((size_t)N * 4);
    float*    gates  = (float*)alloc((size_t)N * 6 * 4);
    int2*     erec   = (int2*)alloc((size_t)E * 8);
    __bf16*   aghi   = (__bf16*)alloc((size_t)N * HID * 2);
    float*    h1     = (float*)alloc((size_t)N * HID * 4);
    _Float16* h16    = (_Float16*)alloc((size_t)N * HID * 2);
    int*      gstart = (int*)alloc((size_t)(G + 1) * 4);
    float*    pooled = (float*)alloc((size_t)G * HID * 4);
    int*      bsum   = (int*)alloc((size_t)NB * 4);
    int*      total  = (int*)alloc(4);
    __bf16*   wpkh0  = (__bf16*)alloc((size_t)EXP * HID * HID * 2);
    __bf16*   wpkh1  = (__bf16*)alloc((size_t)EXP * HID * HID * 2);

    const int* src = ei;
    const int* dst = ei + E;

    hipMemsetAsync(cnt, 0, (size_t)N * 4, stream);
    hipMemsetAsync(pooled, 0, (size_t)G * HID * 4, stream);

    count_kernel<<<(E + 255) / 256, 256, 0, stream>>>(dst, cnt, E);
    dinv_kernel<<<(N + 255) / 256, 256, 0, stream>>>(cnt, dinv, N);
    scan_local_kernel<<<NB, 256, 0, stream>>>(cnt, rowp, bsum, N);
    scan_bsum_kernel<<<1, 64, 0, stream>>>(bsum, NB, total);
    scan_fixup_kernel<<<NB, 256, 0, stream>>>(bsum, total, rowp, cursor, N);
    fill_kernel<<<((E + 255) / 256) * 8, 256, 0, stream>>>(src, dst, cursor, dinv, erec, E);
    gates_kernel<<<(N + 255) / 256, 256, 0, stream>>>(tf, Wg0, Wg1, gates, N);
    pack_w_kernel<<<192, 64, 0, stream>>>(W0, W1, wpkh0, wpkh1);
    f32_to_f16_kernel<<<(N * HID / 4 + 255) / 256, 256, 0, stream>>>(x, h16, N * HID / 4);

    int gemm_blocks = (N + 63) / 64;

    // layer 1: gather x16 -> ag; GEMM writes fp16 h only
    aggregate_kernel<<<N, 128, 0, stream>>>(h16, aghi, rowp, erec, dinv, N);
    expert_gemm_mfma_kernel<<<gemm_blocks, 256, 0, stream>>>(aghi, wpkh0,
                                                             b0, gates, 0, nullptr, h16, N);
    // layer 2: gather h16 -> ag; GEMM writes fp32 h (feeds pooling)
    aggregate_kernel<<<N, 128, 0, stream>>>(h16, aghi, rowp, erec, dinv, N);
    expert_gemm_mfma_kernel<<<gemm_blocks, 256, 0, stream>>>(aghi, wpkh1,
                                                             b1, gates, 3, h1, nullptr, N);

    // pooling + final projection
    find_starts_kernel<<<1, 128, 0, stream>>>(bat, gstart, N, G);
    pool_partial_kernel<<<(N + POOL_CHUNK - 1) / POOL_CHUNK, 128, 0, stream>>>(h1, bat, pooled, N);
    final_kernel<<<G, 64, 0, stream>>>(pooled, gstart, Wf, bf, out);
}

// Round 10
// 332.059 us; speedup vs baseline: 1.2665x; 1.1438x over previous
//
#include <hip/hip_runtime.h>
#include <hip/hip_bf16.h>

#define HID 128
#define EXP 3
#define TOP 4
#define OUTC 64

typedef __bf16 bf16x8 __attribute__((ext_vector_type(8)));
typedef float f32x16 __attribute__((ext_vector_type(16)));
typedef _Float16 half4 __attribute__((ext_vector_type(4)));
typedef _Float16 half8 __attribute__((ext_vector_type(8)));

#define GLDS_STRIDE 272              // staging: 128 bf16 = 256B + 16B pad
#define OUT_STRIDE 132               // out tile: 128 fp32 + 4 pad dwords

// ---------------- CSR build ----------------

__global__ void count_kernel(const int* __restrict__ dst, int* __restrict__ cnt, int E) {
    int i = blockIdx.x * blockDim.x + threadIdx.x;
    if (i < E) atomicAdd(&cnt[dst[i]], 1);
}

__global__ void dinv_kernel(const int* __restrict__ cnt, float* __restrict__ dinv, int N) {
    int n = blockIdx.x * blockDim.x + threadIdx.x;
    if (n < N) dinv[n] = rsqrtf((float)cnt[n] + 1.0f);
}

// ---------------- hierarchical scan ----------------

__global__ __launch_bounds__(256) void scan_local_kernel(const int* __restrict__ cnt,
                                                         int* __restrict__ row_ptr,
                                                         int* __restrict__ bsum, int N) {
    __shared__ int sh[256];
    int b = blockIdx.x;
    int t = threadIdx.x;
    int base = b * 1024 + t * 4;
    int v[4] = {0, 0, 0, 0};
    if (base + 3 < N) {
        int4 c = *(const int4*)(cnt + base);
        v[0] = c.x; v[1] = c.y; v[2] = c.z; v[3] = c.w;
    } else {
#pragma unroll
        for (int k = 0; k < 4; ++k) if (base + k < N) v[k] = cnt[base + k];
    }
    int s = v[0] + v[1] + v[2] + v[3];
    sh[t] = s;
    __syncthreads();
    for (int off = 1; off < 256; off <<= 1) {
        int u = (t >= off) ? sh[t - off] : 0;
        __syncthreads();
        sh[t] += u;
        __syncthreads();
    }
    int run = sh[t] - s;
#pragma unroll
    for (int k = 0; k < 4; ++k) {
        if (base + k < N) row_ptr[base + k] = run;
        run += v[k];
    }
    if (t == 255) bsum[b] = sh[255];
}

__global__ __launch_bounds__(64) void scan_bsum_kernel(int* __restrict__ bsum, int nb,
                                                       int* __restrict__ total) {
    int t = threadIdx.x;
    int carry = 0;
    for (int base = 0; base < nb; base += 64) {
        int i = base + t;
        int v = (i < nb) ? bsum[i] : 0;
        int s = v;
#pragma unroll
        for (int off = 1; off < 64; off <<= 1) {
            int u = __shfl_up(s, off, 64);
            if (t >= off) s += u;
        }
        if (i < nb) bsum[i] = s - v + carry;
        carry += __shfl(s, 63, 64);
    }
    if (t == 0) *total = carry;
}

__global__ __launch_bounds__(256) void scan_fixup_kernel(const int* __restrict__ bsum,
                                                         const int* __restrict__ total,
                                                         int* __restrict__ row_ptr,
                                                         int* __restrict__ cursor, int N) {
    int b = blockIdx.x;
    int t = threadIdx.x;
    int off = bsum[b];
    int base = b * 1024 + t * 4;
#pragma unroll
    for (int k = 0; k < 4; ++k) {
        int i = base + k;
        if (i < N) {
            int r = row_ptr[i] + off;
            row_ptr[i] = r;
            cursor[i] = r;
        }
    }
    if (b == 0 && t == 0) row_ptr[N] = *total;
}

// XCD-sliced fill
__global__ void fill_kernel(const int* __restrict__ src, const int* __restrict__ dst,
                            int* __restrict__ cursor, const float* __restrict__ dinv,
                            int2* __restrict__ erec, int E) {
    int slice = blockIdx.x & 7;
    int i = (blockIdx.x >> 3) * blockDim.x + threadIdx.x;
    if (i >= E) return;
    int d = dst[i];
    if (((d >> 6) & 7) != slice) return;
    int s = src[i];
    int p = atomicAdd(&cursor[d], 1);
    erec[p] = make_int2(s, __float_as_int(dinv[s] * dinv[d]));
}

// ---------------- gates ----------------

__global__ void gates_kernel(const float* __restrict__ tf, const float* __restrict__ Wg0,
                             const float* __restrict__ Wg1, float* __restrict__ gates, int N) {
    int n = blockIdx.x * blockDim.x + threadIdx.x;
    if (n >= N) return;
    float4 t = *(const float4*)(tf + (size_t)n * TOP);
    const float* Wg[2] = {Wg0, Wg1};
#pragma unroll
    for (int l = 0; l < 2; ++l) {
        float lg[EXP];
#pragma unroll
        for (int e = 0; e < EXP; ++e) {
            const float* w = Wg[l] + e * TOP;
            lg[e] = (t.x * w[0] + t.y * w[1] + t.z * w[2] + t.w * w[3]) * (1.0f / 101.0f);
        }
        float m = fmaxf(lg[0], fmaxf(lg[1], lg[2]));
        float e0 = expf(lg[0] - m), e1 = expf(lg[1] - m), e2 = expf(lg[2] - m);
        float inv = 1.0f / (e0 + e1 + e2);
        gates[n * 6 + l * 3 + 0] = e0 * inv;
        gates[n * 6 + l * 3 + 1] = e1 * inv;
        gates[n * 6 + l * 3 + 2] = e2 * inv;
    }
}

// ---------------- fp32 -> fp16 shadow ----------------

__global__ void f32_to_f16_kernel(const float* __restrict__ x, _Float16* __restrict__ y,
                                  int total4) {
    int i = blockIdx.x * blockDim.x + threadIdx.x;
    if (i >= total4) return;
    float4 v = ((const float4*)x)[i];
    half4 h = {(_Float16)v.x, (_Float16)v.y, (_Float16)v.z, (_Float16)v.w};
    ((half4*)y)[i] = h;
}

// ---------------- W pack: B-fragment lane order, single bf16 ----------------

__global__ __launch_bounds__(64) void pack_w_kernel(const float* __restrict__ W0,
                                                    const float* __restrict__ W1,
                                                    __bf16* __restrict__ ph0,
                                                    __bf16* __restrict__ ph1) {
    int bid = blockIdx.x;           // 0..191
    int layer = bid / 96;
    int rem = bid % 96;
    int e = rem / 32;
    int s = (rem % 32) / 4;
    int c = rem % 4;
    const float* W = layer ? W1 : W0;
    __bf16* ph = layer ? ph1 : ph0;
    int l = threadIdx.x;
    size_t dstbase = (size_t)((((e * 8 + s) * 4 + c) * 64 + l)) * 8;
    int kbase = s * 16 + (l >> 5) * 8;
    int n = c * 32 + (l & 31);
#pragma unroll
    for (int j = 0; j < 8; ++j) {
        float w = W[(size_t)e * (HID * HID) + (size_t)(kbase + j) * HID + n];
        ph[dstbase + j] = (__bf16)w;
    }
}

// ---------------- aggregation: ag = A_hat @ h16, output bf16 ----------------
// thread t: 16B chunk (t&15), edge slot (t>>4) -> 8 edges concurrent,
// unroll 2 -> 16 independent dwordx4 gathers in flight per block.

__global__ __launch_bounds__(128) void aggregate_kernel(const _Float16* __restrict__ h16,
                                                        __bf16* __restrict__ aghi,
                                                        const int* __restrict__ row_ptr,
                                                        const int2* __restrict__ erec,
                                                        const float* __restrict__ dinv, int N) {
    __shared__ float red[2][HID];
    int n = blockIdx.x;
    int t = threadIdx.x;
    int c16 = t & 15;
    int slot = t >> 4;
    int s = row_ptr[n], e = row_ptr[n + 1];

    float acc[8];
#pragma unroll
    for (int j = 0; j < 8; ++j) acc[j] = 0.f;

    int i = s + slot;
    for (; i + 8 < e; i += 16) {
        int2 r0 = erec[i], r1 = erec[i + 8];
        float w0 = __int_as_float(r0.y), w1 = __int_as_float(r1.y);
        half8 v0 = *(const half8*)(h16 + (size_t)r0.x * HID + c16 * 8);
        half8 v1 = *(const half8*)(h16 + (size_t)r1.x * HID + c16 * 8);
#pragma unroll
        for (int j = 0; j < 8; ++j)
            acc[j] += (float)v0[j] * w0 + (float)v1[j] * w1;
    }
    if (i < e) {
        int2 r0 = erec[i];
        float w0 = __int_as_float(r0.y);
        half8 v0 = *(const half8*)(h16 + (size_t)r0.x * HID + c16 * 8);
#pragma unroll
        for (int j = 0; j < 8; ++j) acc[j] += (float)v0[j] * w0;
    }

    // combine the 4 slots within each wave (slots differ by lane^16, lane^32)
#pragma unroll
    for (int j = 0; j < 8; ++j) acc[j] += __shfl_xor(acc[j], 16, 64);
#pragma unroll
    for (int j = 0; j < 8; ++j) acc[j] += __shfl_xor(acc[j], 32, 64);

    int wv = t >> 6;
    int lane = t & 63;
    if (lane < 16) {
#pragma unroll
        for (int j = 0; j < 8; ++j) red[wv][lane * 8 + j] = acc[j];
    }
    __syncthreads();

    float dn = dinv[n];
    float a = red[0][t] + red[1][t] + (float)h16[(size_t)n * HID + t] * dn * dn;
    aghi[(size_t)n * HID + t] = (__bf16)a;
}

// ---------------- MFMA fused 3-expert GEMM + relu + gate ----------------
// 64-row tile; out-tile staged in LDS; outputs any of: fp32 stream, fp16
// stream, fused mean-pool partial sums (batch sorted -> few atomics/block).

__global__ __launch_bounds__(256, 4) void expert_gemm_mfma_kernel(
        const __bf16* __restrict__ aghi,
        const __bf16* __restrict__ wpkh,
        const float* __restrict__ bias, const float* __restrict__ gates, int gate_off,
        float* __restrict__ hout32, _Float16* __restrict__ hout16,
        const int* __restrict__ batch, float* __restrict__ pooled, int N) {
    __shared__ char lds[64 * OUT_STRIDE * 4];   // 33792 B; staging uses first 17408
    int tid = threadIdx.x;
    int row0 = blockIdx.x * 64;

#pragma unroll
    for (int it = 0; it < 4; ++it) {
        int id = tid + it * 256;
        int r = id >> 4;
        int c = id & 15;
        int gr = row0 + r;
        float4 vh = make_float4(0.f, 0.f, 0.f, 0.f);
        if (gr < N) vh = ((const float4*)aghi)[(size_t)gr * 16 + c];
        *(float4*)(lds + r * GLDS_STRIDE + c * 16) = vh;
    }
    __syncthreads();

    int lane = tid & 63;
    int wave = tid >> 6;
    int m = lane & 31;
    int g = lane >> 5;
    int rhalf = wave & 1;
    int chalf = wave >> 1;
    const char* arow = lds + (rhalf * 32 + m) * GLDS_STRIDE + g * 16;
    int rowbase = row0 + rhalf * 32 + 4 * g;

    float F[2][16];
#pragma unroll
    for (int c = 0; c < 2; ++c)
#pragma unroll
        for (int r = 0; r < 16; ++r) F[c][r] = 0.f;

    for (int e = 0; e < EXP; ++e) {
        f32x16 acc[2];
#pragma unroll
        for (int c = 0; c < 2; ++c)
#pragma unroll
            for (int r = 0; r < 16; ++r) acc[c][r] = 0.f;

#pragma unroll
        for (int s = 0; s < 8; ++s) {
            bf16x8 Ah = *(const bf16x8*)(arow + s * 32);
#pragma unroll
            for (int c = 0; c < 2; ++c) {
                int cp = chalf * 2 + c;
                bf16x8 Bh = *(const bf16x8*)(wpkh + (size_t)(((e * 8 + s) * 4 + cp) * 64 + lane) * 8);
                acc[c] = __builtin_amdgcn_mfma_f32_32x32x16_bf16(Ah, Bh, acc[c], 0, 0, 0);
            }
        }
        float gt[16];
#pragma unroll
        for (int r = 0; r < 16; ++r) {
            int rr = rowbase + (r & 3) + 8 * (r >> 2);
            gt[r] = (rr < N) ? gates[(size_t)rr * 6 + gate_off + e] : 0.f;
        }
#pragma unroll
        for (int c = 0; c < 2; ++c) {
            float bb = bias[e * HID + chalf * 64 + c * 32 + m];
#pragma unroll
            for (int r = 0; r < 16; ++r)
                F[c][r] += gt[r] * fmaxf(acc[c][r] + bb, 0.f);
        }
    }

    // ---- fragments -> LDS out-tile ----
    __syncthreads();
    float* lds32 = (float*)lds;
#pragma unroll
    for (int c = 0; c < 2; ++c) {
        int colg = chalf * 64 + c * 32 + m;
#pragma unroll
        for (int r = 0; r < 16; ++r) {
            int lr = rhalf * 32 + 4 * g + (r & 3) + 8 * (r >> 2);
            lds32[lr * OUT_STRIDE + colg] = F[c][r];
        }
    }
    __syncthreads();

    if (hout32) {
#pragma unroll
        for (int it = 0; it < 8; ++it) {
            int id = tid + it * 256;
            int r = id >> 5;
            int c4 = id & 31;
            int gr = row0 + r;
            if (gr < N) {
                float4 v = *(const float4*)(&lds32[r * OUT_STRIDE + c4 * 4]);
                *(float4*)(hout32 + (size_t)gr * HID + c4 * 4) = v;
            }
        }
    }
    if (hout16) {
#pragma unroll
        for (int it = 0; it < 8; ++it) {
            int id = tid + it * 256;
            int r = id >> 5;
            int c4 = id & 31;
            int gr = row0 + r;
            if (gr < N) {
                const float* src = &lds32[r * OUT_STRIDE + c4 * 4];
                half4 v = {(_Float16)src[0], (_Float16)src[1],
                           (_Float16)src[2], (_Float16)src[3]};
                *(half4*)(hout16 + (size_t)gr * HID + c4 * 4) = v;
            }
        }
    }
    if (pooled) {
        // fused mean-pool partials: thread = (col, row-half of 32)
        int col = tid & 127;
        int rbase = (tid >> 7) * 32;
        int cur = -1;
        float acc = 0.f;
        for (int r = 0; r < 32; ++r) {
            int gr = row0 + rbase + r;
            if (gr >= N) break;
            int gb = batch[gr];
            if (gb != cur) {
                if (cur >= 0) atomicAdd(&pooled[cur * HID + col], acc);
                acc = 0.f;
                cur = gb;
            }
            acc += lds32[(rbase + r) * OUT_STRIDE + col];
        }
        if (cur >= 0) atomicAdd(&pooled[cur * HID + col], acc);
    }
}

// ---------------- pooling + final ----------------

__global__ void find_starts_kernel(const int* __restrict__ batch, int* __restrict__ gstart,
                                   int N, int G) {
    int g = blockIdx.x * blockDim.x + threadIdx.x;
    if (g > G) return;
    if (g == G) { gstart[G] = N; return; }
    int lo = 0, hi = N;
    while (lo < hi) {
        int mid = (lo + hi) >> 1;
        if (batch[mid] < g) lo = mid + 1; else hi = mid;
    }
    gstart[g] = lo;
}

__global__ __launch_bounds__(64) void final_kernel(const float* __restrict__ pooled,
                                                   const int* __restrict__ gstart,
                                                   const float* __restrict__ Wf,
                                                   const float* __restrict__ bf,
                                                   float* __restrict__ out) {
    __shared__ float ps[HID];
    int g = blockIdx.x;
    int o = threadIdx.x;
    float invc = 1.0f / fmaxf((float)(gstart[g + 1] - gstart[g]), 1.0f);
    ps[o] = pooled[g * HID + o] * invc;
    ps[o + 64] = pooled[g * HID + o + 64] * invc;
    __syncthreads();
    float acc = bf[o];
#pragma unroll 8
    for (int k = 0; k < HID; ++k) acc = fmaf(ps[k], Wf[k * OUTC + o], acc);
    out[g * OUTC + o] = acc;
}

// ---------------- launch ----------------

extern "C" void kernel_launch(void* const* d_in, const int* in_sizes, int n_in,
                              void* d_out, int out_size, void* d_ws, size_t ws_size,
                              hipStream_t stream) {
    const float* x   = (const float*)d_in[0];
    const float* tf  = (const float*)d_in[1];
    const int*   ei  = (const int*)d_in[2];
    const int*   bat = (const int*)d_in[3];
    const float* W0  = (const float*)d_in[4];
    const float* b0  = (const float*)d_in[5];
    const float* Wg0 = (const float*)d_in[6];
    const float* W1  = (const float*)d_in[7];
    const float* b1  = (const float*)d_in[8];
    const float* Wg1 = (const float*)d_in[9];
    const float* Wf  = (const float*)d_in[10];
    const float* bf  = (const float*)d_in[11];
    float* out = (float*)d_out;

    const int N = in_sizes[0] / HID;       // 50000
    const int E = in_sizes[2] / 2;         // 800000
    const int G = out_size / OUTC;         // 64
    const int NB = (N + 1023) / 1024;

    char* p = (char*)d_ws;
    auto alloc = [&](size_t bytes) -> void* {
        void* r = (void*)p;
        p += (bytes + 255) & ~(size_t)255;
        return r;
    };
    float*    dinv   = (float*)alloc((size_t)N * 4);
    int*      cnt    = (int*)alloc((size_t)N * 4);
    int*      rowp   = (int*)alloc((size_t)(N + 1) * 4);
    int*      cursor = (int*)alloc((size_t)N * 4);
    float*    gates  = (float*)alloc((size_t)N * 6 * 4);
    int2*     erec   = (int2*)alloc((size_t)E * 8);
    __bf16*   aghi   = (__bf16*)alloc((size_t)N * HID * 2);
    _Float16* h16    = (_Float16*)alloc((size_t)N * HID * 2);
    int*      gstart = (int*)alloc((size_t)(G + 1) * 4);
    float*    pooled = (float*)alloc((size_t)G * HID * 4);
    int*      bsum   = (int*)alloc((size_t)NB * 4);
    int*      total  = (int*)alloc(4);
    __bf16*   wpkh0  = (__bf16*)alloc((size_t)EXP * HID * HID * 2);
    __bf16*   wpkh1  = (__bf16*)alloc((size_t)EXP * HID * HID * 2);

    const int* src = ei;
    const int* dst = ei + E;

    hipMemsetAsync(cnt, 0, (size_t)N * 4, stream);
    hipMemsetAsync(pooled, 0, (size_t)G * HID * 4, stream);

    count_kernel<<<(E + 255) / 256, 256, 0, stream>>>(dst, cnt, E);
    dinv_kernel<<<(N + 255) / 256, 256, 0, stream>>>(cnt, dinv, N);
    scan_local_kernel<<<NB, 256, 0, stream>>>(cnt, rowp, bsum, N);
    scan_bsum_kernel<<<1, 64, 0, stream>>>(bsum, NB, total);
    scan_fixup_kernel<<<NB, 256, 0, stream>>>(bsum, total, rowp, cursor, N);
    fill_kernel<<<((E + 255) / 256) * 8, 256, 0, stream>>>(src, dst, cursor, dinv, erec, E);
    gates_kernel<<<(N + 255) / 256, 256, 0, stream>>>(tf, Wg0, Wg1, gates, N);
    pack_w_kernel<<<192, 64, 0, stream>>>(W0, W1, wpkh0, wpkh1);
    f32_to_f16_kernel<<<(N * HID / 4 + 255) / 256, 256, 0, stream>>>(x, h16, N * HID / 4);
    find_starts_kernel<<<1, 128, 0, stream>>>(bat, gstart, N, G);

    int gemm_blocks = (N + 63) / 64;

    // layer 1: gather x16 -> ag; GEMM writes fp16 h only
    aggregate_kernel<<<N, 128, 0, stream>>>(h16, aghi, rowp, erec, dinv, N);
    expert_gemm_mfma_kernel<<<gemm_blocks, 256, 0, stream>>>(aghi, wpkh0, b0, gates, 0,
                                                             nullptr, h16, nullptr, nullptr, N);
    // layer 2: gather h16 -> ag; GEMM pools directly (no h materialization)
    aggregate_kernel<<<N, 128, 0, stream>>>(h16, aghi, rowp, erec, dinv, N);
    expert_gemm_mfma_kernel<<<gemm_blocks, 256, 0, stream>>>(aghi, wpkh1, b1, gates, 3,
                                                             nullptr, nullptr, bat, pooled, N);

    // final projection
    final_kernel<<<G, 64, 0, stream>>>(pooled, gstart, Wf, bf, out);
}